// Round 11
// baseline (388.813 us; speedup 1.0000x reference)
//
#include <hip/hip_runtime.h>

#define EPSF 1e-5f

// ---------------- workspace layout (float offsets) ----------------
#define P1S 0          // [20][4096]
#define P1Q 81920
#define P2S 163840     // [40][1024]
#define P2Q 204800
#define P3S 245760     // [60][256]
#define P3Q 261120
#define P4S 276480     // [80][36]
#define P4Q 279360
#define SC1 282240
#define SH1 282260
#define SC2 282280
#define SH2 282320
#define SC3 282360
#define SH3 282420
#define SC4 282480
#define SH4 282560
#define SC5 282640     // [768]
#define SH5 283408

#define OFF_A 524288            // pool2 / lcT / featB (19.6M cap)
#define OFF_B 20205568          // pool1 / hT (4.9M cap)
#define OFF_C 25125888          // h (x1): 752,640
#define OFF_D 25878528          // x2: 737,280
#define OFF_Y 26615808          // y: 196,608

#define KP 6144                 // padded K for bf16 GEMM

// ---------------- helpers ----------------
__device__ __forceinline__ void blockReduce2(float& v1, float& v2) {
  __syncthreads();
  #pragma unroll
  for (int off = 32; off > 0; off >>= 1) {
    v1 += __shfl_down(v1, off);
    v2 += __shfl_down(v2, off);
  }
  __shared__ float s1[4], s2[4];
  const int wid = threadIdx.x >> 6, lane = threadIdx.x & 63;
  if (lane == 0) { s1[wid] = v1; s2[wid] = v2; }
  __syncthreads();
  if (threadIdx.x == 0) { v1 = s1[0]+s1[1]+s1[2]+s1[3]; v2 = s2[0]+s2[1]+s2[2]+s2[3]; }
}

__device__ __forceinline__ void waveReduce2(float& a, float& b) {
  #pragma unroll
  for (int off = 32; off > 0; off >>= 1) {
    a += __shfl_down(a, off);
    b += __shfl_down(b, off);
  }
}

__device__ __forceinline__ unsigned short f2bf(float f) {
  unsigned int u = __float_as_uint(f);
  return (unsigned short)((u + 0x7FFFu + ((u >> 16) & 1u)) >> 16);
}

// ---------------- conv1 stats: pool-window layout, wave-reduce only ----------
__global__ __launch_bounds__(256) void conv1_stats_kernel(
    const float* __restrict__ x, const float* __restrict__ w, const float* __restrict__ cb,
    float* __restrict__ ps, float* __restrict__ pq) {
  const int sp = blockIdx.x * 256 + threadIdx.x;  // pooled pixel, 961
  const int c0 = blockIdx.y * 5, b = blockIdx.z;
  __shared__ float wsh[5][27];
  if (threadIdx.x < 135) wsh[threadIdx.x / 27][threadIdx.x % 27] = w[c0 * 27 + threadIdx.x];
  __syncthreads();
  float s[5] = {}, q[5] = {};
  if (sp < 961) {
    const int py = sp / 31, px = sp - py * 31;
    const float* xb = x + (size_t)b * 3 * 4096 + (2 * py) * 64 + 2 * px;
    float acc[5][4] = {};
    #pragma unroll
    for (int ic = 0; ic < 3; ic++) {
      float v[4][4];
      #pragma unroll
      for (int r = 0; r < 4; r++)
        #pragma unroll
        for (int cc = 0; cc < 4; cc++)
          v[r][cc] = xb[ic * 4096 + r * 64 + cc];
      #pragma unroll
      for (int ol = 0; ol < 5; ol++)
        #pragma unroll
        for (int dy = 0; dy < 2; dy++)
          #pragma unroll
          for (int dx = 0; dx < 2; dx++) {
            float a = acc[ol][dy * 2 + dx];
            #pragma unroll
            for (int ky = 0; ky < 3; ky++)
              #pragma unroll
              for (int kx = 0; kx < 3; kx++)
                a = fmaf(v[dy + ky][dx + kx], wsh[ol][(ic * 3 + ky) * 3 + kx], a);
            acc[ol][dy * 2 + dx] = a;
          }
    }
    #pragma unroll
    for (int ol = 0; ol < 5; ol++) {
      const float base = cb[c0 + ol];
      #pragma unroll
      for (int k = 0; k < 4; k++) {
        const float vv = acc[ol][k] + base;
        s[ol] += vv; q[ol] += vv * vv;
      }
    }
  }
  #pragma unroll
  for (int ol = 0; ol < 5; ol++) waveReduce2(s[ol], q[ol]);
  const int lane = threadIdx.x & 63, wid = threadIdx.x >> 6;
  if (lane == 0) {
    const int slot = b * 16 + blockIdx.x * 4 + wid;
    #pragma unroll
    for (int ol = 0; ol < 5; ol++) {
      ps[(c0 + ol) * 4096 + slot] = s[ol];
      pq[(c0 + ol) * 4096 + slot] = q[ol];
    }
  }
}

// ---------------- fused conv1 + BN + ReLU + pool (recompute) ----------------
__global__ __launch_bounds__(256) void convpool1_kernel(
    const float* __restrict__ x, const float* __restrict__ w, const float* __restrict__ cb,
    const float* __restrict__ scale, const float* __restrict__ shift,
    float* __restrict__ out) {
  const int sp = blockIdx.x * 256 + threadIdx.x;  // pooled pixel, 961
  const int c0 = blockIdx.y * 5, b = blockIdx.z;
  __shared__ float wsh[5][27];
  if (threadIdx.x < 135) wsh[threadIdx.x / 27][threadIdx.x % 27] = w[c0 * 27 + threadIdx.x];
  __syncthreads();
  if (sp >= 961) return;
  const int py = sp / 31, px = sp - py * 31;
  const float* xb = x + (size_t)b * 3 * 4096 + (2 * py) * 64 + 2 * px;
  float acc[5][4] = {};
  #pragma unroll
  for (int ic = 0; ic < 3; ic++) {
    float v[4][4];
    #pragma unroll
    for (int r = 0; r < 4; r++)
      #pragma unroll
      for (int cc = 0; cc < 4; cc++)
        v[r][cc] = xb[ic * 4096 + r * 64 + cc];
    #pragma unroll
    for (int ol = 0; ol < 5; ol++)
      #pragma unroll
      for (int dy = 0; dy < 2; dy++)
        #pragma unroll
        for (int dx = 0; dx < 2; dx++) {
          float a = acc[ol][dy * 2 + dx];
          #pragma unroll
          for (int ky = 0; ky < 3; ky++)
            #pragma unroll
            for (int kx = 0; kx < 3; kx++)
              a = fmaf(v[dy + ky][dx + kx], wsh[ol][(ic * 3 + ky) * 3 + kx], a);
          acc[ol][dy * 2 + dx] = a;
        }
  }
  #pragma unroll
  for (int ol = 0; ol < 5; ol++) {
    const float sc = scale[c0 + ol];
    const float sh = fmaf(cb[c0 + ol], sc, shift[c0 + ol]);
    float m = -1e30f;
    #pragma unroll
    for (int k = 0; k < 4; k++)
      m = fmaxf(m, fmaxf(fmaf(acc[ol][k], sc, sh), 0.f));
    out[(size_t)(b * 20 + c0 + ol) * 961 + sp] = m;
  }
}

// ---------------- conv2 stats: pool-window layout, wave-reduce ----------------
__global__ __launch_bounds__(256) void conv2_stats_kernel(
    const float* __restrict__ in, const float* __restrict__ w, const float* __restrict__ cb,
    float* __restrict__ ps, float* __restrict__ pq) {
  const int sp = threadIdx.x;  // pooled pixel, 225
  const int c0 = blockIdx.y * 8, b = blockIdx.z;
  __shared__ float4 wsh4[8][20];
  for (int e = threadIdx.x; e < 160; e += 256)
    wsh4[e / 20][e % 20] = ((const float4*)w)[c0 * 20 + e];
  __syncthreads();
  float s[8] = {}, q[8] = {};
  if (sp < 225) {
    const int py = sp / 15, px = sp - py * 15;
    const float* ib = in + (size_t)b * 20 * 961 + (2 * py) * 31 + 2 * px;
    float acc[8][4] = {};
    #pragma unroll 4
    for (int ic = 0; ic < 20; ic++) {
      float v[3][3];
      #pragma unroll
      for (int r = 0; r < 3; r++)
        #pragma unroll
        for (int cc = 0; cc < 3; cc++)
          v[r][cc] = ib[ic * 961 + r * 31 + cc];
      #pragma unroll
      for (int ol = 0; ol < 8; ol++) {
        const float4 wv = wsh4[ol][ic];
        #pragma unroll
        for (int dy = 0; dy < 2; dy++)
          #pragma unroll
          for (int dx = 0; dx < 2; dx++) {
            float a = acc[ol][dy * 2 + dx];
            a = fmaf(v[dy][dx],     wv.x, a);
            a = fmaf(v[dy][dx + 1], wv.y, a);
            a = fmaf(v[dy + 1][dx], wv.z, a);
            a = fmaf(v[dy + 1][dx + 1], wv.w, a);
            acc[ol][dy * 2 + dx] = a;
          }
      }
    }
    #pragma unroll
    for (int ol = 0; ol < 8; ol++) {
      const float base = cb[c0 + ol];
      #pragma unroll
      for (int k = 0; k < 4; k++) {
        const float vv = acc[ol][k] + base;
        s[ol] += vv; q[ol] += vv * vv;
      }
    }
  }
  #pragma unroll
  for (int ol = 0; ol < 8; ol++) waveReduce2(s[ol], q[ol]);
  const int lane = threadIdx.x & 63, wid = threadIdx.x >> 6;
  if (lane == 0) {
    const int slot = b * 4 + wid;
    #pragma unroll
    for (int ol = 0; ol < 8; ol++) {
      ps[(c0 + ol) * 1024 + slot] = s[ol];
      pq[(c0 + ol) * 1024 + slot] = q[ol];
    }
  }
}

// ---------------- fused conv2 + BN + ReLU + pool (recompute) ----------------
__global__ __launch_bounds__(256) void convpool2_kernel(
    const float* __restrict__ in, const float* __restrict__ w, const float* __restrict__ cb,
    const float* __restrict__ scale, const float* __restrict__ shift,
    float* __restrict__ out) {
  const int sp = threadIdx.x;  // 225
  const int c0 = blockIdx.y * 8, b = blockIdx.z;
  __shared__ float4 wsh4[8][20];
  for (int e = threadIdx.x; e < 160; e += 256)
    wsh4[e / 20][e % 20] = ((const float4*)w)[c0 * 20 + e];
  __syncthreads();
  if (sp >= 225) return;
  const int py = sp / 15, px = sp - py * 15;
  const float* ib = in + (size_t)b * 20 * 961 + (2 * py) * 31 + 2 * px;
  float acc[8][4] = {};
  #pragma unroll 4
  for (int ic = 0; ic < 20; ic++) {
    float v[3][3];
    #pragma unroll
    for (int r = 0; r < 3; r++)
      #pragma unroll
      for (int cc = 0; cc < 3; cc++)
        v[r][cc] = ib[ic * 961 + r * 31 + cc];
    #pragma unroll
    for (int ol = 0; ol < 8; ol++) {
      const float4 wv = wsh4[ol][ic];
      #pragma unroll
      for (int dy = 0; dy < 2; dy++)
        #pragma unroll
        for (int dx = 0; dx < 2; dx++) {
          float a = acc[ol][dy * 2 + dx];
          a = fmaf(v[dy][dx],     wv.x, a);
          a = fmaf(v[dy][dx + 1], wv.y, a);
          a = fmaf(v[dy + 1][dx], wv.z, a);
          a = fmaf(v[dy + 1][dx + 1], wv.w, a);
          acc[ol][dy * 2 + dx] = a;
        }
    }
  }
  #pragma unroll
  for (int ol = 0; ol < 8; ol++) {
    const float sc = scale[c0 + ol];
    const float sh = fmaf(cb[c0 + ol], sc, shift[c0 + ol]);
    float m = -1e30f;
    #pragma unroll
    for (int k = 0; k < 4; k++)
      m = fmaxf(m, fmaxf(fmaf(acc[ol][k], sc, sh), 0.f));
    out[(size_t)(b * 40 + c0 + ol) * 225 + sp] = m;
  }
}

// ---------------- conv3 stats: pool-window, 4 batches/block, wave-reduce -------
__global__ __launch_bounds__(256) void conv3_stats_kernel(
    const float* __restrict__ in, const float* __restrict__ w, const float* __restrict__ cb,
    float* __restrict__ ps, float* __restrict__ pq) {
  const int tid = threadIdx.x;
  const int c0 = blockIdx.y * 6, bq = blockIdx.z;  // bq in [0,64)
  __shared__ float4 wsh4[6][40];
  if (tid < 240) wsh4[tid / 40][tid % 40] = ((const float4*)w)[c0 * 40 + tid];
  __syncthreads();
  float s[6] = {}, q[6] = {};
  if (tid < 196) {
    const int bl = tid / 49, sp = tid - bl * 49;
    const int b = bq * 4 + bl;
    const int py = sp / 7, px = sp - py * 7;
    const float* ib = in + (size_t)b * 40 * 225 + (2 * py) * 15 + 2 * px;
    float acc[6][4] = {};
    #pragma unroll 4
    for (int ic = 0; ic < 40; ic++) {
      float v[3][3];
      #pragma unroll
      for (int r = 0; r < 3; r++)
        #pragma unroll
        for (int cc = 0; cc < 3; cc++)
          v[r][cc] = ib[ic * 225 + r * 15 + cc];
      #pragma unroll
      for (int ol = 0; ol < 6; ol++) {
        const float4 wv = wsh4[ol][ic];
        #pragma unroll
        for (int dy = 0; dy < 2; dy++)
          #pragma unroll
          for (int dx = 0; dx < 2; dx++) {
            float a = acc[ol][dy * 2 + dx];
            a = fmaf(v[dy][dx],     wv.x, a);
            a = fmaf(v[dy][dx + 1], wv.y, a);
            a = fmaf(v[dy + 1][dx], wv.z, a);
            a = fmaf(v[dy + 1][dx + 1], wv.w, a);
            acc[ol][dy * 2 + dx] = a;
          }
      }
    }
    #pragma unroll
    for (int ol = 0; ol < 6; ol++) {
      const float base = cb[c0 + ol];
      #pragma unroll
      for (int k = 0; k < 4; k++) {
        const float vv = acc[ol][k] + base;
        s[ol] += vv; q[ol] += vv * vv;
      }
    }
  }
  #pragma unroll
  for (int ol = 0; ol < 6; ol++) waveReduce2(s[ol], q[ol]);
  const int lane = threadIdx.x & 63, wid = threadIdx.x >> 6;
  if (lane == 0) {
    const int slot = bq * 4 + wid;  // 256 slots
    #pragma unroll
    for (int ol = 0; ol < 6; ol++) {
      ps[(c0 + ol) * 256 + slot] = s[ol];
      pq[(c0 + ol) * 256 + slot] = q[ol];
    }
  }
}

// ---------------- fused conv3 + BN + ReLU + pool (recompute), writes h --------
__global__ __launch_bounds__(256) void convpool3_kernel(
    const float* __restrict__ in, const float* __restrict__ w, const float* __restrict__ cb,
    const float* __restrict__ scale, const float* __restrict__ shift,
    float* __restrict__ out) {
  const int tid = threadIdx.x;
  const int c0 = blockIdx.y * 6, bq = blockIdx.z;
  __shared__ float4 wsh4[6][40];
  if (tid < 240) wsh4[tid / 40][tid % 40] = ((const float4*)w)[c0 * 40 + tid];
  __syncthreads();
  if (tid >= 196) return;
  const int bl = tid / 49, sp = tid - bl * 49;
  const int b = bq * 4 + bl;
  const int py = sp / 7, px = sp - py * 7;
  const float* ib = in + (size_t)b * 40 * 225 + (2 * py) * 15 + 2 * px;
  float acc[6][4] = {};
  #pragma unroll 4
  for (int ic = 0; ic < 40; ic++) {
    float v[3][3];
    #pragma unroll
    for (int r = 0; r < 3; r++)
      #pragma unroll
      for (int cc = 0; cc < 3; cc++)
        v[r][cc] = ib[ic * 225 + r * 15 + cc];
    #pragma unroll
    for (int ol = 0; ol < 6; ol++) {
      const float4 wv = wsh4[ol][ic];
      #pragma unroll
      for (int dy = 0; dy < 2; dy++)
        #pragma unroll
        for (int dx = 0; dx < 2; dx++) {
          float a = acc[ol][dy * 2 + dx];
          a = fmaf(v[dy][dx],     wv.x, a);
          a = fmaf(v[dy][dx + 1], wv.y, a);
          a = fmaf(v[dy + 1][dx], wv.z, a);
          a = fmaf(v[dy + 1][dx + 1], wv.w, a);
          acc[ol][dy * 2 + dx] = a;
        }
    }
  }
  #pragma unroll
  for (int ol = 0; ol < 6; ol++) {
    const float sc = scale[c0 + ol];
    const float sh = fmaf(cb[c0 + ol], sc, shift[c0 + ol]);
    float m = -1e30f;
    #pragma unroll
    for (int k = 0; k < 4; k++)
      m = fmaxf(m, fmaxf(fmaf(acc[ol][k], sc, sh), 0.f));
    out[(size_t)(b * 60 + c0 + ol) * 49 + sp] = m;
  }
}

// ---------------- BN finalize: partials -> scale/shift ----------------
template<int SLOTS>
__global__ __launch_bounds__(256) void bnfin_kernel(
    const float* __restrict__ ps, const float* __restrict__ pq,
    const float* __restrict__ g, const float* __restrict__ bet,
    float* __restrict__ scale, float* __restrict__ shift, float invN) {
  const int c = blockIdx.x;
  float s = 0.f, q = 0.f;
  for (int i = threadIdx.x; i < SLOTS; i += 256) { s += ps[c * SLOTS + i]; q += pq[c * SLOTS + i]; }
  blockReduce2(s, q);
  if (threadIdx.x == 0) {
    const float m = s * invN;
    const float var = q * invN - m * m;
    const float sc = g[c] * rsqrtf(var + EPSF);
    scale[c] = sc;
    shift[c] = bet[c] - m * sc;
  }
}

// ---------------- transpose h [256][2940] -> hT [2940][256] ----------------
__global__ __launch_bounds__(256) void transpose_h_kernel(
    const float* __restrict__ in, float* __restrict__ out) {
  __shared__ float tile[64][65];
  const int lx = threadIdx.x & 63, ly = threadIdx.x >> 6;
  const int c0 = blockIdx.x * 64;   // cp dim (2940)
  const int r0 = blockIdx.y * 64;   // b dim (256)
  #pragma unroll
  for (int i = 0; i < 16; i++) {
    const int b = r0 + ly + i * 4;
    const int cp = c0 + lx;
    tile[ly + i * 4][lx] = (cp < 2940) ? in[(size_t)b * 2940 + cp] : 0.f;
  }
  __syncthreads();
  #pragma unroll
  for (int i = 0; i < 16; i++) {
    const int cp = c0 + ly + i * 4;
    if (cp < 2940) out[(size_t)cp * 256 + r0 + lx] = tile[lx][ly + i * 4];
  }
}

// ---------------- LocallyConnected2d (coalesced, o-tiled) ----------------
__global__ __launch_bounds__(256) void lc2_kernel(
    const float* __restrict__ hT, const float* __restrict__ w, const float* __restrict__ lb,
    float* __restrict__ outT, float* __restrict__ ps, float* __restrict__ pq) {
  const int sp = blockIdx.x;
  const int o0 = blockIdx.y * 8;
  const int b = threadIdx.x;
  __shared__ float wsh[8 * 240];
  for (int e = threadIdx.x; e < 1920; e += 256) {
    const int ol = e / 240, ck = e - ol * 240;
    const int c = ck >> 2, k = ck & 3;
    wsh[e] = w[((size_t)((o0 + ol) * 60 + c) * 36 + sp) * 4 + k];
  }
  __syncthreads();
  const int i = sp / 6, j = sp - i * 6;
  const int pos0 = i * 7 + j;
  float acc[8] = {};
  #pragma unroll 4
  for (int c = 0; c < 60; c++) {
    const float h0 = hT[(size_t)(c * 49 + pos0) * 256 + b];
    const float h1 = hT[(size_t)(c * 49 + pos0 + 1) * 256 + b];
    const float h2 = hT[(size_t)(c * 49 + pos0 + 7) * 256 + b];
    const float h3 = hT[(size_t)(c * 49 + pos0 + 8) * 256 + b];
    #pragma unroll
    for (int ol = 0; ol < 8; ol++) {
      const float* wp = &wsh[ol * 240 + c * 4];
      acc[ol] = fmaf(h0, wp[0], acc[ol]);
      acc[ol] = fmaf(h1, wp[1], acc[ol]);
      acc[ol] = fmaf(h2, wp[2], acc[ol]);
      acc[ol] = fmaf(h3, wp[3], acc[ol]);
    }
  }
  #pragma unroll
  for (int ol = 0; ol < 8; ol++) {
    const int o = o0 + ol;
    const float val = acc[ol] + lb[o * 36 + sp];
    outT[(size_t)(o * 36 + sp) * 256 + b] = val;
    float v1 = val, v2 = val * val;
    blockReduce2(v1, v2);
    if (threadIdx.x == 0) { ps[o * 36 + sp] = v1; pq[o * 36 + sp] = v2; }
  }
}

// ---------------- lcpost: BN+ReLU + transpose lcT [2880][256] -> x2 [256][2880] ----
__global__ __launch_bounds__(256) void lcpost2_kernel(
    const float* __restrict__ inT, float* __restrict__ out,
    const float* __restrict__ scale, const float* __restrict__ shift) {
  __shared__ float tile[64][65];
  const int lx = threadIdx.x & 63, ly = threadIdx.x >> 6;
  const int k0 = blockIdx.x * 64;   // k dim (2880)
  const int b0 = blockIdx.y * 64;   // b dim (256)
  #pragma unroll
  for (int i = 0; i < 16; i++) {
    const int k = k0 + ly + i * 4;
    const int o = k / 36;
    const float v = inT[(size_t)k * 256 + b0 + lx];
    tile[ly + i * 4][lx] = fmaxf(fmaf(v, scale[o], shift[o]), 0.f);
  }
  __syncthreads();
  #pragma unroll
  for (int i = 0; i < 16; i++) {
    const int b = b0 + ly + i * 4;
    out[(size_t)b * 2880 + k0 + lx] = tile[lx][ly + i * 4];
  }
}

// ---------------- pack feat [256][KP] bf16 from h(2940) + x2(2880), zero tail ----
__global__ __launch_bounds__(256) void pack_feat_kernel(
    const float* __restrict__ h, const float* __restrict__ x2, unsigned short* __restrict__ fB) {
  const int idx = blockIdx.x * 256 + threadIdx.x;  // 256*1536 exact
  const int b = idx / 1536, kq = idx - b * 1536;
  const int k0 = kq * 4;
  ushort4 o;
  float v[4];
  #pragma unroll
  for (int q = 0; q < 4; q++) {
    const int k = k0 + q;
    v[q] = (k < 2940) ? h[(size_t)b * 2940 + k]
         : (k < 5820) ? x2[(size_t)b * 2880 + (k - 2940)] : 0.f;
  }
  o.x = f2bf(v[0]); o.y = f2bf(v[1]); o.z = f2bf(v[2]); o.w = f2bf(v[3]);
  *(ushort4*)&fB[(size_t)b * KP + k0] = o;
}

// ---------------- FC GEMM via bf16 MFMA, W converted in-register --------------
typedef __attribute__((ext_vector_type(4))) float f32x4;
typedef __attribute__((ext_vector_type(8))) short bf16x8;

__device__ __forceinline__ bf16x8 ld_w_bf16(const float* __restrict__ row, int kidx) {
  bf16x8 r;
  if (kidx + 8 <= 5820) {
    const float4 f0 = *(const float4*)(row + kidx);
    const float4 f1 = *(const float4*)(row + kidx + 4);
    r[0] = (short)f2bf(f0.x); r[1] = (short)f2bf(f0.y);
    r[2] = (short)f2bf(f0.z); r[3] = (short)f2bf(f0.w);
    r[4] = (short)f2bf(f1.x); r[5] = (short)f2bf(f1.y);
    r[6] = (short)f2bf(f1.z); r[7] = (short)f2bf(f1.w);
  } else {
    #pragma unroll
    for (int i = 0; i < 8; i++) {
      const float v = (kidx + i < 5820) ? row[kidx + i] : 0.f;
      r[i] = (short)f2bf(v);
    }
  }
  return r;
}

__global__ __launch_bounds__(256) void fc_mfma_kernel(
    const unsigned short* __restrict__ fB, const float* __restrict__ W,
    float* __restrict__ Y) {
  const int wid = threadIdx.x >> 6, l = threadIdx.x & 63;
  const int wy = wid >> 1, wx = wid & 1;
  const int m0 = blockIdx.x * 64 + wy * 32;
  const int n0 = blockIdx.y * 64 + wx * 32;
  const int lrow = l & 15, lk = (l >> 4) * 8;
  const unsigned short* ap = fB + (size_t)(m0 + lrow) * KP + lk;
  const float* w0 = W + (size_t)(n0 + lrow) * 5820;
  const float* w1 = W + (size_t)(n0 + lrow + 16) * 5820;
  f32x4 acc[2][2] = {};
  const int kbase = blockIdx.z * 1536;
  #pragma unroll 2
  for (int s = 0; s < 48; s++) {
    const int k = kbase + s * 32;
    const int kidx = k + lk;
    const bf16x8 a0 = *(const bf16x8*)(ap + k);
    const bf16x8 a1 = *(const bf16x8*)(ap + 16 * KP + k);
    const bf16x8 b0 = ld_w_bf16(w0, kidx);
    const bf16x8 b1 = ld_w_bf16(w1, kidx);
    acc[0][0] = __builtin_amdgcn_mfma_f32_16x16x32_bf16(a0, b0, acc[0][0], 0, 0, 0);
    acc[0][1] = __builtin_amdgcn_mfma_f32_16x16x32_bf16(a0, b1, acc[0][1], 0, 0, 0);
    acc[1][0] = __builtin_amdgcn_mfma_f32_16x16x32_bf16(a1, b0, acc[1][0], 0, 0, 0);
    acc[1][1] = __builtin_amdgcn_mfma_f32_16x16x32_bf16(a1, b1, acc[1][1], 0, 0, 0);
  }
  const int orow = (l >> 4) * 4, ocol = l & 15;
  #pragma unroll
  for (int fi = 0; fi < 2; fi++)
    #pragma unroll
    for (int fj = 0; fj < 2; fj++)
      #pragma unroll
      for (int r = 0; r < 4; r++)
        atomicAdd(&Y[(size_t)(m0 + fi * 16 + orow + r) * 768 + n0 + fj * 16 + ocol],
                  acc[fi][fj][r]);
}

// ---------------- BN5 stats (per-feature over batch), coalesced ----------------
__global__ __launch_bounds__(256) void bn5_stats_kernel(
    const float* __restrict__ Y, const float* __restrict__ g, const float* __restrict__ bet,
    float* __restrict__ scale, float* __restrict__ shift) {
  const int tx = threadIdx.x & 63, ty = threadIdx.x >> 6;
  const int n = blockIdx.x * 64 + tx;
  float s = 0.f, q = 0.f;
  for (int bi = 0; bi < 64; bi++) {
    const float v = Y[(size_t)(bi * 4 + ty) * 768 + n];
    s += v; q += v * v;
  }
  __shared__ float rs[4][64], rq[4][64];
  rs[ty][tx] = s; rq[ty][tx] = q;
  __syncthreads();
  if (ty == 0) {
    s = rs[0][tx] + rs[1][tx] + rs[2][tx] + rs[3][tx];
    q = rq[0][tx] + rq[1][tx] + rq[2][tx] + rq[3][tx];
    const float m = s * (1.f / 256.f);
    const float var = q * (1.f / 256.f) - m * m;
    const float sc = g[n] * rsqrtf(var + EPSF);
    scale[n] = sc;
    shift[n] = bet[n] - m * sc;
  }
}

// ---------------- final fuse ----------------
__global__ __launch_bounds__(256) void final_kernel(
    const float* __restrict__ Y, const float* __restrict__ scale, const float* __restrict__ shift,
    const float* __restrict__ fw, const float* __restrict__ fb, float* __restrict__ out) {
  const int idx = blockIdx.x * 256 + threadIdx.x;  // 12288 exact
  const int b = idx / 48, hh = idx - b * 48;
  const float* yb = Y + (size_t)b * 768 + hh * 16;
  const float* sc = scale + hh * 16;
  const float* sh = shift + hh * 16;
  const float* w = fw + hh * 16;
  float acc = fb[hh];
  #pragma unroll
  for (int s = 0; s < 16; s++)
    acc += fmaxf(fmaf(yb[s], sc[s], sh[s]), 0.f) * w[s];
  out[idx] = acc;
}

// ---------------- launch ----------------
extern "C" void kernel_launch(void* const* d_in, const int* in_sizes, int n_in,
                              void* d_out, int out_size, void* d_ws, size_t ws_size,
                              hipStream_t stream) {
  const float* x   = (const float*)d_in[0];
  const float* c1w = (const float*)d_in[1];
  const float* c1b = (const float*)d_in[2];
  const float* g1  = (const float*)d_in[3];
  const float* b1  = (const float*)d_in[4];
  const float* c2w = (const float*)d_in[5];
  const float* c2b = (const float*)d_in[6];
  const float* g2  = (const float*)d_in[7];
  const float* b2  = (const float*)d_in[8];
  const float* c3w = (const float*)d_in[9];
  const float* c3b = (const float*)d_in[10];
  const float* g3  = (const float*)d_in[11];
  const float* b3  = (const float*)d_in[12];
  const float* lcw = (const float*)d_in[13];
  const float* lcb = (const float*)d_in[14];
  const float* g4  = (const float*)d_in[15];
  const float* b4  = (const float*)d_in[16];
  const float* fcw = (const float*)d_in[17];
  const float* g5  = (const float*)d_in[19];
  const float* b5  = (const float*)d_in[20];
  const float* fw  = (const float*)d_in[21];
  const float* fb  = (const float*)d_in[22];

  float* ws = (float*)d_ws;
  float* A  = ws + OFF_A;   // pool2 / lcT / featB
  float* B_ = ws + OFF_B;   // pool1 / hT
  float* C_ = ws + OFF_C;   // h (x1)
  float* D_ = ws + OFF_D;   // x2
  float* Y  = ws + OFF_Y;
  unsigned short* featB = (unsigned short*)A;  // 256*KP bf16 = 786432 floats

  hipMemsetAsync(Y, 0, 196608 * sizeof(float), stream);

  // stage 1
  conv1_stats_kernel<<<dim3(4, 4, 256), 256, 0, stream>>>(x, c1w, c1b, ws + P1S, ws + P1Q);
  bnfin_kernel<4096><<<20, 256, 0, stream>>>(ws + P1S, ws + P1Q, g1, b1, ws + SC1, ws + SH1, 1.f / 984064.f);
  convpool1_kernel<<<dim3(4, 4, 256), 256, 0, stream>>>(x, c1w, c1b, ws + SC1, ws + SH1, B_);
  // stage 2
  conv2_stats_kernel<<<dim3(1, 5, 256), 256, 0, stream>>>(B_, c2w, c2b, ws + P2S, ws + P2Q);
  bnfin_kernel<1024><<<40, 256, 0, stream>>>(ws + P2S, ws + P2Q, g2, b2, ws + SC2, ws + SH2, 1.f / 230400.f);
  convpool2_kernel<<<dim3(1, 5, 256), 256, 0, stream>>>(B_, c2w, c2b, ws + SC2, ws + SH2, A);
  // stage 3: stats + recompute, writes pooled h directly into C_
  conv3_stats_kernel<<<dim3(1, 10, 64), 256, 0, stream>>>(A, c3w, c3b, ws + P3S, ws + P3Q);
  bnfin_kernel<256><<<60, 256, 0, stream>>>(ws + P3S, ws + P3Q, g3, b3, ws + SC3, ws + SH3, 1.f / 50176.f);
  convpool3_kernel<<<dim3(1, 10, 64), 256, 0, stream>>>(A, c3w, c3b, ws + SC3, ws + SH3, C_);
  // h -> hT (B_ free after stage-2 consumers)
  transpose_h_kernel<<<dim3(46, 4), 256, 0, stream>>>(C_, B_);
  // locally connected: lcT into A (pool2 dead after convpool3)
  lc2_kernel<<<dim3(36, 10), 256, 0, stream>>>(B_, lcw, lcb, A, ws + P4S, ws + P4Q);
  bnfin_kernel<36><<<80, 256, 0, stream>>>(ws + P4S, ws + P4Q, g4, b4, ws + SC4, ws + SH4, 1.f / 9216.f);
  lcpost2_kernel<<<dim3(45, 4), 256, 0, stream>>>(A, D_, ws + SC4, ws + SH4);
  // fc via bf16 MFMA; W converted in-kernel (pack_w removed)
  pack_feat_kernel<<<1536, 256, 0, stream>>>(C_, D_, featB);
  fc_mfma_kernel<<<dim3(4, 12, 4), 256, 0, stream>>>(featB, fcw, Y);
  bn5_stats_kernel<<<12, 256, 0, stream>>>(Y, g5, b5, ws + SC5, ws + SH5);
  final_kernel<<<48, 256, 0, stream>>>(Y, ws + SC5, ws + SH5, fw, fb, (float*)d_out);
}